// Round 4
// baseline (289.523 us; speedup 1.0000x reference)
//
#include <hip/hip_runtime.h>
#include <hip/hip_bf16.h>

typedef __attribute__((ext_vector_type(8))) short bf16x8;
typedef __attribute__((ext_vector_type(4))) float f32x4;
typedef unsigned short u16;
typedef unsigned int u32;

#define NP 34                                           // 32 + 2 halo
#define XT_BYTES ((size_t)4 * NP * NP * NP * 128 * 2)   // 40,247,296 B

__device__ __forceinline__ u16 f2bf(float f) {
  __hip_bfloat16 h = __float2bfloat16(f);
  return __builtin_bit_cast(u16, h);
}

__device__ __forceinline__ void gload_lds16(const u16* g, u16* l) {
  __builtin_amdgcn_global_load_lds(
      (const __attribute__((address_space(1))) u32*)g,
      (__attribute__((address_space(3))) u32*)l, 16, 0, 0);
}

#define WAITV(N) asm volatile("s_waitcnt vmcnt(" #N ")" ::: "memory")
#define BAR() do { __builtin_amdgcn_s_barrier(); asm volatile("" ::: "memory"); } while (0)

// ---------------- kernel 1: demod + modulated bf16 weights ----------------
__global__ __launch_bounds__(128) void kmodw(const float* __restrict__ w,
                                             const float* __restrict__ y,
                                             u16* __restrict__ wmod) {
  const int oc = blockIdx.x, b = blockIdx.y;
  const int ic = threadIdx.x;               // 128 threads
  const float* wp = w + (oc * 128 + ic) * 27;
  float wv[27];
  float s = 0.f;
#pragma unroll
  for (int t = 0; t < 27; ++t) { wv[t] = wp[t]; s += wv[t] * wv[t]; }
  const float yv = y[b * 128 + ic];
  float v = yv * yv * s;
#pragma unroll
  for (int m = 1; m < 64; m <<= 1) v += __shfl_xor(v, m);
  __shared__ float part[2];
  const int lane = ic & 63, wid = ic >> 6;
  if (lane == 0) part[wid] = v;
  __syncthreads();
  const float demod = rsqrtf(part[0] + part[1] + 1e-8f);
  const float sc = yv * demod;
#pragma unroll
  for (int t = 0; t < 27; ++t)
    wmod[((b * 27 + t) * 128 + oc) * 128 + ic] = f2bf(wv[t] * sc);
}

// ---------------- kernel 2: zero only the halo of xt ----------------------
__global__ __launch_bounds__(128) void khalo(u16* __restrict__ xt) {
  const int zy = blockIdx.x, b = blockIdx.y;
  const int zz = zy / NP, yy = zy % NP;
  u16* row = xt + ((size_t)((b * NP + zz) * NP + yy) * NP) * 128;
  u32* wp = (u32*)row;
  if (zz == 0 || zz == NP - 1 || yy == 0 || yy == NP - 1) {
#pragma unroll
    for (int i = 0; i < 17; ++i) wp[i * 128 + threadIdx.x] = 0;
  } else {
    if (threadIdx.x < 64) wp[threadIdx.x] = 0;
    else ((u32*)(row + 33 * 128))[threadIdx.x - 64] = 0;
  }
}

// ---------------- kernel 3: f32 -> bf16 transpose-cast (interior) ----------
__global__ __launch_bounds__(256) void kcastx(const float* __restrict__ x,
                                              u16* __restrict__ xt) {
  const int yq = blockIdx.x, z = blockIdx.y, b = blockIdx.z;
  const int tid = threadIdx.x;
  __shared__ u16 t[32 * 132];
  const float* xp = x + (size_t)b * 128 * 32768 + (z * 32 + yq) * 32;
#pragma unroll
  for (int p = 0; p < 16; ++p) {
    const int ic = p * 8 + (tid >> 5), xx = tid & 31;
    t[xx * 132 + ic] = f2bf(xp[(size_t)ic * 32768 + xx]);
  }
  __syncthreads();
  u16* xtb = xt + (((size_t)(b * NP + z + 1) * NP + (yq + 1)) * NP + 1) * 128;
#pragma unroll
  for (int p = 0; p < 4; ++p) {
    const int xx = p * 8 + (tid >> 5), icq = tid & 31;
    *(ushort4*)(xtb + (size_t)xx * 128 + icq * 4) = *(const ushort4*)&t[xx * 132 + icq * 4];
  }
}

// ---------------- kernel 4: high-ratio pipelined implicit-GEMM conv -------
// Block: 128 oc x 512 n (2z x 8y x 32x), 8 waves (1x8), wave tile 128x64.
// K in ic-quarters (32). B staged per (dz,quarter) over full (dy,dx) halo
// (rows [2zz][10jy][40px], reused 9x). 108 phases, counted vmcnt, A 2-ahead.
__global__ __launch_bounds__(512, 2) void kconv(const u16* __restrict__ xt,
                                                const u16* __restrict__ wmod,
                                                float* __restrict__ out) {
  __shared__ __align__(16) u16 Asm[2][512 * 8];    // 2 x 8 KiB (A ic-quarter)
  __shared__ __align__(16) u16 Bsm[2][3584 * 8];   // 2 x 56 KiB (B dz-quarter)
  const int tid = threadIdx.x;                     // 0..511
  const int lane = tid & 63, wn = tid >> 6;        // 8 waves along n
  const int l15 = lane & 15, sg = lane >> 4;       // frag col / k-slot
  const int bsw = ((blockIdx.x & 7) << 5) + (blockIdx.x >> 3);  // 256 blocks
  const int yt = bsw & 3, zt = (bsw >> 2) & 15, b = bsw >> 6;
  const int y0 = yt << 3, z0 = zt << 1;

  const u16* xb = xt + (size_t)b * (NP * NP * NP) * 128;
  const u16* wb = wmod + (size_t)b * 27 * 16384;

  f32x4 acc[8][4];
#pragma unroll
  for (int i = 0; i < 8; ++i)
#pragma unroll
    for (int j = 0; j < 4; ++j) acc[i][j] = (f32x4){0.f, 0.f, 0.f, 0.f};

  // per-wave B base rows: n = 64*wn + 16*nf + l15; zz=wn>>2, yy=2*(wn&3)+(nf>>1)
  int r0[4];
#pragma unroll
  for (int nf = 0; nf < 4; ++nf)
    r0[nf] = (((wn >> 2) * 10) + ((wn & 3) << 1) + (nf >> 1)) * 40 +
             ((nf & 1) << 4) + l15;

  // stage A ic-quarter: [128 oc][32 ic] = 512 slots, 1 load/thread
  auto stageA = [&](int t, int qq, int par) {
    const int oc = tid >> 2, jj = tid & 3;
    const int sga = (jj - (oc >> 1)) & 3;
    gload_lds16(wb + t * 16384 + (oc << 7) + (qq << 5) + (sga << 3),
                &Asm[par][tid << 3]);
  };
  // stage B (dz, quarter): rows r=(zz*10+jy)*40+px (800 real, pad to 896), 7 loads/thread
  auto stageB = [&](int jb, int par) {
    const int dzi = jb >> 2, qq = jb & 3;
    const int izb = z0 + dzi;
#pragma unroll
    for (int k = 0; k < 7; ++k) {
      const int s = (k << 9) + tid;
      int r = s >> 2;
      const int jj = s & 3;
      r = r < 800 ? r : 799;                        // pad slots, never read
      const int zz = r / 400;
      const int rem = r - zz * 400;
      const int jy = rem / 40;
      int px = rem - jy * 40;
      px = px < 34 ? px : 33;                       // pad px, never read
      const int sgb = (jj - (r >> 1)) & 3;
      gload_lds16(xb + ((size_t)((izb + zz) * NP + (y0 + jy)) * NP + px) * 128 +
                      (qq << 5) + (sgb << 3),
                  &Bsm[par][s << 3]);
    }
  };

#define COMP(APAR, BPAR, DYI, DXI)                                            \
  {                                                                           \
    const u16* Ah = &Asm[APAR][0];                                            \
    const u16* Bh = &Bsm[BPAR][0];                                            \
    bf16x8 af[8], bv[4];                                                      \
    _Pragma("unroll") for (int m = 0; m < 8; ++m) {                           \
      const int oc = (m << 4) + l15;                                          \
      af[m] = *(const bf16x8*)&Ah[(oc << 5) + (((sg + (oc >> 1)) & 3) << 3)]; \
    }                                                                         \
    _Pragma("unroll") for (int nf = 0; nf < 4; ++nf) {                        \
      const int r = r0[nf] + (DYI) * 40 + (DXI);                              \
      bv[nf] = *(const bf16x8*)&Bh[(r << 5) + (((sg + (r >> 1)) & 3) << 3)];  \
    }                                                                         \
    __builtin_amdgcn_s_setprio(1);                                            \
    _Pragma("unroll") for (int m = 0; m < 8; ++m)                             \
      _Pragma("unroll") for (int nf = 0; nf < 4; ++nf)                        \
        acc[m][nf] = __builtin_amdgcn_mfma_f32_16x16x32_bf16(                 \
            af[m], bv[nf], acc[m][nf], 0, 0, 0);                              \
    __builtin_amdgcn_s_setprio(0);                                            \
  }

// phase step: wait -> barrier -> compute -> barrier -> issue B? -> issue A(P+2)?
#define STEP(p9, NW, DOB, DOA)                                                \
  {                                                                           \
    WAITV(NW); BAR();                                                         \
    COMP((j + (p9)) & 1, j & 1, (p9) / 3, (p9) % 3);                          \
    BAR();                                                                    \
    if (DOB) stageB(j + 1, (j + 1) & 1);                                      \
    if (DOA) {                                                                \
      const int jn = j + ((p9) >= 7 ? 1 : 0);                                 \
      stageA((jn >> 2) * 9 + ((p9) + 2) % 9, jn & 3, (j + (p9)) & 1);         \
    }                                                                         \
  }

  // prologue: B(0) [7 loads], A(P=0) [1], A(P=1) [1]
  stageB(0, 0);
  stageA(0, 0, 0);
  stageA(1, 0, 1);

  for (int j = 0; j < 11; ++j) {        // steady groups (tap quarter-groups)
    STEP(0, 1, false, true);
    STEP(1, 1, false, true);
    STEP(2, 1, true,  true);            // issue B(j+1) 7 phases early
    STEP(3, 8, false, true);            // allow B(j+1)+A in flight
    STEP(4, 1, false, true);
    STEP(5, 1, false, true);
    STEP(6, 1, false, true);
    STEP(7, 1, false, true);
    STEP(8, 1, false, true);
  }
  {                                     // tail group j = 11
    const int j = 11;
    STEP(0, 1, false, true);
    STEP(1, 1, false, true);
    STEP(2, 1, false, true);
    STEP(3, 1, false, true);
    STEP(4, 1, false, true);
    STEP(5, 1, false, true);
    STEP(6, 1, false, true);            // issues A(107), the last one
    STEP(7, 1, false, false);
    STEP(8, 0, false, false);
  }

  // epilogue: C/D col=lane&15 (n), row=(lane>>4)*4+reg (oc within 16)
#pragma unroll
  for (int m = 0; m < 8; ++m) {
    const int ocb = (m << 4) + (sg << 2);
#pragma unroll
    for (int nf = 0; nf < 4; ++nf) {
      const int n = (wn << 6) + (nf << 4) + l15;
      const int zz = n >> 8, yy = (n >> 5) & 7, xx = n & 31;
      float* op = out + ((size_t)(b * 128 + ocb) << 15) + ((z0 + zz) << 10) +
                  ((y0 + yy) << 5) + xx;
#pragma unroll
      for (int r = 0; r < 4; ++r) op[(size_t)r << 15] = acc[m][nf][r];
    }
  }
#undef COMP
#undef STEP
}

extern "C" void kernel_launch(void* const* d_in, const int* in_sizes, int n_in,
                              void* d_out, int out_size, void* d_ws, size_t ws_size,
                              hipStream_t stream) {
  const float* x = (const float*)d_in[0];
  const float* y = (const float*)d_in[1];
  const float* w = (const float*)d_in[2];
  float* out = (float*)d_out;
  u16* xt = (u16*)d_ws;
  u16* wmod = (u16*)((char*)d_ws + XT_BYTES);

  hipLaunchKernelGGL(khalo, dim3(NP * NP, 4), dim3(128), 0, stream, xt);
  hipLaunchKernelGGL(kmodw, dim3(128, 4), dim3(128), 0, stream, w, y, wmod);
  hipLaunchKernelGGL(kcastx, dim3(32, 32, 4), dim3(256), 0, stream, x, xt);
  hipLaunchKernelGGL(kconv, dim3(256), dim3(512), 0, stream, xt, wmod, out);
}

// Round 5
// 160.368 us; speedup vs baseline: 1.8054x; 1.8054x over previous
//
#include <hip/hip_runtime.h>
#include <hip/hip_bf16.h>

typedef __attribute__((ext_vector_type(8))) short bf16x8;
typedef __attribute__((ext_vector_type(4))) float f32x4;
typedef unsigned short u16;
typedef unsigned int u32;

#define NP 34                                           // 32 + 2 halo
#define XT_BYTES ((size_t)4 * NP * NP * NP * 128 * 2)   // 40,247,296 B

__device__ __forceinline__ u16 f2bf(float f) {
  __hip_bfloat16 h = __float2bfloat16(f);
  return __builtin_bit_cast(u16, h);
}

__device__ __forceinline__ void gload_lds16(const u16* g, u16* l) {
  __builtin_amdgcn_global_load_lds(
      (const __attribute__((address_space(1))) u32*)g,
      (__attribute__((address_space(3))) u32*)l, 16, 0, 0);
}

#define WAITV(N) asm volatile("s_waitcnt vmcnt(" #N ")" ::: "memory")
#define BAR() do { __builtin_amdgcn_s_barrier(); asm volatile("" ::: "memory"); } while (0)

// ---------------- kernel 1: demod + modulated bf16 weights ----------------
__global__ __launch_bounds__(128) void kmodw(const float* __restrict__ w,
                                             const float* __restrict__ y,
                                             u16* __restrict__ wmod) {
  const int oc = blockIdx.x, b = blockIdx.y;
  const int ic = threadIdx.x;               // 128 threads
  const float* wp = w + (oc * 128 + ic) * 27;
  float wv[27];
  float s = 0.f;
#pragma unroll
  for (int t = 0; t < 27; ++t) { wv[t] = wp[t]; s += wv[t] * wv[t]; }
  const float yv = y[b * 128 + ic];
  float v = yv * yv * s;
#pragma unroll
  for (int m = 1; m < 64; m <<= 1) v += __shfl_xor(v, m);
  __shared__ float part[2];
  const int lane = ic & 63, wid = ic >> 6;
  if (lane == 0) part[wid] = v;
  __syncthreads();
  const float demod = rsqrtf(part[0] + part[1] + 1e-8f);
  const float sc = yv * demod;
#pragma unroll
  for (int t = 0; t < 27; ++t)
    wmod[((b * 27 + t) * 128 + oc) * 128 + ic] = f2bf(wv[t] * sc);
}

// ---------------- kernel 2: zero only the halo of xt ----------------------
__global__ __launch_bounds__(128) void khalo(u16* __restrict__ xt) {
  const int zy = blockIdx.x, b = blockIdx.y;
  const int zz = zy / NP, yy = zy % NP;
  u16* row = xt + ((size_t)((b * NP + zz) * NP + yy) * NP) * 128;
  u32* wp = (u32*)row;
  if (zz == 0 || zz == NP - 1 || yy == 0 || yy == NP - 1) {
#pragma unroll
    for (int i = 0; i < 17; ++i) wp[i * 128 + threadIdx.x] = 0;
  } else {
    if (threadIdx.x < 64) wp[threadIdx.x] = 0;
    else ((u32*)(row + 33 * 128))[threadIdx.x - 64] = 0;
  }
}

// ---------------- kernel 3: f32 -> bf16 transpose-cast (interior) ----------
__global__ __launch_bounds__(256) void kcastx(const float* __restrict__ x,
                                              u16* __restrict__ xt) {
  const int yq = blockIdx.x, z = blockIdx.y, b = blockIdx.z;
  const int tid = threadIdx.x;
  __shared__ u16 t[32 * 132];
  const float* xp = x + (size_t)b * 128 * 32768 + (z * 32 + yq) * 32;
#pragma unroll
  for (int p = 0; p < 16; ++p) {
    const int ic = p * 8 + (tid >> 5), xx = tid & 31;
    t[xx * 132 + ic] = f2bf(xp[(size_t)ic * 32768 + xx]);
  }
  __syncthreads();
  u16* xtb = xt + (((size_t)(b * NP + z + 1) * NP + (yq + 1)) * NP + 1) * 128;
#pragma unroll
  for (int p = 0; p < 4; ++p) {
    const int xx = p * 8 + (tid >> 5), icq = tid & 31;
    *(ushort4*)(xtb + (size_t)xx * 128 + icq * 4) = *(const ushort4*)&t[xx * 132 + icq * 4];
  }
}

// ---------------- kernel 4: B-direct implicit-GEMM conv -------------------
// Block: 128 oc x 256 n (8y x 32x) at fixed (b,z). 4 waves, 1x4 grid, wave
// tile 128x64. A (wmod) in LDS, half-tap dbuf, staged 2 phases ahead.
// B read DIRECTLY from xt (L2) into registers, double-buffered (T14).
// 54 phases; per phase WAITV(12) drains only A(p); no vmcnt(0) in loop.
__global__ __launch_bounds__(256, 2) void kconv(const u16* __restrict__ xt,
                                                const u16* __restrict__ wmod,
                                                float* __restrict__ out) {
  __shared__ __align__(16) u16 Asm[2][1024 * 8];   // 2 x 16 KiB [oc][64 ic]
  const int tid = threadIdx.x;
  const int lane = tid & 63, wn = tid >> 6;        // 4 waves along n
  const int l15 = lane & 15, sg = lane >> 4;
  const int bsw = ((blockIdx.x & 7) << 6) + (blockIdx.x >> 3);  // XCD chunks
  const int yt = bsw & 3, z = (bsw >> 2) & 31, b = bsw >> 7;
  const int y0 = yt << 3;

  const u16* wb = wmod + (size_t)b * 27 * 16384;
  const char* xbp = (const char*)(xt + (size_t)b * (NP * NP * NP) * 128);

  // per-lane B base byte offsets (dz=dy=dx=0, h=0, kk=0)
  int bofs[4];
#pragma unroll
  for (int nf = 0; nf < 4; ++nf) {
    const int yy = (wn << 1) + (nf >> 1);
    const int xx = ((nf & 1) << 4) + l15;
    bofs[nf] = (((z + 1) * NP + (y0 + yy + 1)) * NP + (xx + 1)) * 256 + (sg << 4);
  }

  f32x4 acc[8][4];
#pragma unroll
  for (int i = 0; i < 8; ++i)
#pragma unroll
    for (int j = 0; j < 4; ++j) acc[i][j] = (f32x4){0.f, 0.f, 0.f, 0.f};

  // stage A half-tap: [128 oc][64 ic] = 1024 slots, 4 loads/thread
  auto stageA = [&](int tap, int h) {
#pragma unroll
    for (int k = 0; k < 4; ++k) {
      const int s = (k << 8) + tid;
      const int oc = s >> 3, jp = s & 7, jg = jp ^ (oc & 7);
      gload_lds16(wb + tap * 16384 + (oc << 7) + (h << 6) + (jg << 3),
                  &Asm[h][s << 3]);
    }
  };
  // load 8 B fragments (4 nf x 2 kk) straight from global
  auto loadB = [&](bf16x8* bv, int toff) {
#pragma unroll
    for (int nf = 0; nf < 4; ++nf)
#pragma unroll
      for (int kk = 0; kk < 2; ++kk)
        bv[nf * 2 + kk] =
            *(const bf16x8*)(xbp + (bofs[nf] + toff + (kk << 6)));
  };

#define COMPUTE(PAR, BV)                                                     \
  {                                                                          \
    _Pragma("unroll") for (int kk = 0; kk < 2; ++kk) {                       \
      bf16x8 af[8];                                                          \
      _Pragma("unroll") for (int m = 0; m < 8; ++m) {                        \
        const int oc = (m << 4) + l15;                                       \
        const int jp = ((kk << 2) + sg) ^ (oc & 7);                          \
        af[m] = *(const bf16x8*)&Asm[PAR][(oc << 6) + (jp << 3)];            \
      }                                                                      \
      __builtin_amdgcn_s_setprio(1);                                         \
      _Pragma("unroll") for (int m = 0; m < 8; ++m)                          \
        _Pragma("unroll") for (int nf = 0; nf < 4; ++nf)                     \
          acc[m][nf] = __builtin_amdgcn_mfma_f32_16x16x32_bf16(              \
              af[m], (BV)[nf * 2 + kk], acc[m][nf], 0, 0, 0);                \
      __builtin_amdgcn_s_setprio(0);                                         \
    }                                                                        \
  }

  bf16x8 bvE[8], bvO[8];
  // prologue: A(0,h0) 4, A(0,h1) 4, bvE(tap0,h0) 8  -> 16 outstanding
  stageA(0, 0);
  stageA(0, 1);
  {
    const int t0 = ((-1 * NP - 1) * NP - 1) * 256;       // tap 0 = (-1,-1,-1)
    loadB(bvE, t0);
  }

  for (int tap = 0; tap < 27; ++tap) {
    const int dz = tap / 9 - 1, dy = (tap / 3) % 3 - 1, dx = tap % 3 - 1;
    const int t0 = ((dz * NP + dy) * NP + dx) * 256;
    const int tn = tap < 26 ? tap + 1 : 26;
    const int dz2 = tn / 9 - 1, dy2 = (tn / 3) % 3 - 1, dx2 = tn % 3 - 1;
    const int t1 = ((dz2 * NP + dy2) * NP + dx2) * 256;

    // ---- phase p = 2*tap (h=0, uses Asm[0], bvE) ----
    WAITV(12); BAR();
    loadB(bvO, t0 + 128);            // prefetch (tap, h=1)
    COMPUTE(0, bvE);
    BAR();
    if (tap < 26) stageA(tap + 1, 0);

    // ---- phase p = 2*tap+1 (h=1, uses Asm[1], bvO) ----
    if (tap < 26) { WAITV(12); } else { WAITV(8); }
    BAR();
    loadB(bvE, t1);                  // prefetch (tap+1, h=0) (dummy at tap=26)
    COMPUTE(1, bvO);
    BAR();
    if (tap < 26) stageA(tap + 1, 1);
  }

  // epilogue: C/D col=l15 (n), row=sg*4+r (oc within 16)
#pragma unroll
  for (int m = 0; m < 8; ++m) {
    const int ocb = (m << 4) + (sg << 2);
#pragma unroll
    for (int nf = 0; nf < 4; ++nf) {
      const int n = (wn << 6) + (nf << 4) + l15;
      const int yy = n >> 5, xx = n & 31;
      float* op = out + ((size_t)(b * 128 + ocb) << 15) + (z << 10) +
                  ((y0 + yy) << 5) + xx;
#pragma unroll
      for (int r = 0; r < 4; ++r) op[(size_t)r << 15] = acc[m][nf][r];
    }
  }
#undef COMPUTE
}

extern "C" void kernel_launch(void* const* d_in, const int* in_sizes, int n_in,
                              void* d_out, int out_size, void* d_ws, size_t ws_size,
                              hipStream_t stream) {
  const float* x = (const float*)d_in[0];
  const float* y = (const float*)d_in[1];
  const float* w = (const float*)d_in[2];
  float* out = (float*)d_out;
  u16* xt = (u16*)d_ws;
  u16* wmod = (u16*)((char*)d_ws + XT_BYTES);

  hipLaunchKernelGGL(khalo, dim3(NP * NP, 4), dim3(128), 0, stream, xt);
  hipLaunchKernelGGL(kmodw, dim3(128, 4), dim3(128), 0, stream, w, y, wmod);
  hipLaunchKernelGGL(kcastx, dim3(32, 32, 4), dim3(256), 0, stream, x, xt);
  hipLaunchKernelGGL(kconv, dim3(512), dim3(256), 0, stream, xt, wmod, out);
}

// Round 6
// 158.274 us; speedup vs baseline: 1.8293x; 1.0132x over previous
//
#include <hip/hip_runtime.h>
#include <hip/hip_bf16.h>

typedef __attribute__((ext_vector_type(8))) short bf16x8;
typedef __attribute__((ext_vector_type(4))) float f32x4;
typedef unsigned short u16;
typedef unsigned int u32;

#define NP 34                                           // 32 + 2 halo
#define XT_HALF_ELEMS ((size_t)4 * NP * NP * NP * 64)   // 10,061,824 u16
#define XT_HALF_BYTES (4 * NP * NP * NP * 128)          // 20,123,648 B (int-safe)
#define XT_BYTES ((size_t)2 * XT_HALF_ELEMS * 2)        // 40,247,296 B

__device__ __forceinline__ u16 f2bf(float f) {
  __hip_bfloat16 h = __float2bfloat16(f);
  return __builtin_bit_cast(u16, h);
}

__device__ __forceinline__ void gload_lds16(const u16* g, u16* l) {
  __builtin_amdgcn_global_load_lds(
      (const __attribute__((address_space(1))) u32*)g,
      (__attribute__((address_space(3))) u32*)l, 16, 0, 0);
}

#define WAITV(N) asm volatile("s_waitcnt vmcnt(" #N ")" ::: "memory")
#define BAR() do { __builtin_amdgcn_s_barrier(); asm volatile("" ::: "memory"); } while (0)

// ---------------- kernel 1: demod + modulated bf16 weights ----------------
// wmod[h][b][tap][oc][64] = bf16( weight[oc][ic][tap] * y[b][ic] * demod[b][oc] )
__global__ __launch_bounds__(128) void kmodw(const float* __restrict__ w,
                                             const float* __restrict__ y,
                                             u16* __restrict__ wmod) {
  const int oc = blockIdx.x, b = blockIdx.y;
  const int ic = threadIdx.x;               // 128 threads
  const float* wp = w + (oc * 128 + ic) * 27;
  float wv[27];
  float s = 0.f;
#pragma unroll
  for (int t = 0; t < 27; ++t) { wv[t] = wp[t]; s += wv[t] * wv[t]; }
  const float yv = y[b * 128 + ic];
  float v = yv * yv * s;
#pragma unroll
  for (int m = 1; m < 64; m <<= 1) v += __shfl_xor(v, m);
  __shared__ float part[2];
  const int lane = ic & 63, wid = ic >> 6;
  if (lane == 0) part[wid] = v;
  __syncthreads();
  const float demod = rsqrtf(part[0] + part[1] + 1e-8f);
  const float sc = yv * demod;
  const int h = ic >> 6, icr = ic & 63;
#pragma unroll
  for (int t = 0; t < 27; ++t)
    wmod[((size_t)((h * 4 + b) * 27 + t) << 13) + (oc << 6) + icr] =
        f2bf(wv[t] * sc);
}

// ---------------- kernel 2: zero only the halo of xt (both halves) --------
__global__ __launch_bounds__(128) void khalo(u16* __restrict__ xt) {
  const int zy = blockIdx.x, b = blockIdx.y;
  const int zz = zy / NP, yy = zy % NP;
  const int tid = threadIdx.x;
#pragma unroll
  for (int h = 0; h < 2; ++h) {
    u16* row = xt + (size_t)h * XT_HALF_ELEMS +
               ((size_t)((b * NP + zz) * NP + yy) * NP) * 64;
    u32* wp = (u32*)row;                    // 34*64 u16 = 1088 u32
    if (zz == 0 || zz == NP - 1 || yy == 0 || yy == NP - 1) {
#pragma unroll
      for (int i = 0; i < 9; ++i) {
        const int idx = i * 128 + tid;
        if (idx < 1088) wp[idx] = 0;
      }
    } else {
      if (tid < 32) wp[tid] = 0;                       // x = 0 col
      else if (tid < 64) wp[33 * 32 + (tid - 32)] = 0; // x = 33 col
    }
  }
}

// ---------------- kernel 3: f32 -> bf16 transpose-cast (interior) ----------
// x[b][ic][z][y][x] (f32) -> xt[h][b][z+1][y+1][x+1][64] (bf16)
__global__ __launch_bounds__(256) void kcastx(const float* __restrict__ x,
                                              u16* __restrict__ xt) {
  const int yq = blockIdx.x, z = blockIdx.y, b = blockIdx.z;
  const int tid = threadIdx.x;
  __shared__ u16 t[32 * 132];
  const float* xp = x + (size_t)b * 128 * 32768 + (z * 32 + yq) * 32;
#pragma unroll
  for (int p = 0; p < 16; ++p) {
    const int ic = p * 8 + (tid >> 5), xx = tid & 31;
    t[xx * 132 + ic] = f2bf(xp[(size_t)ic * 32768 + xx]);
  }
  __syncthreads();
#pragma unroll
  for (int p = 0; p < 4; ++p) {
    const int xx = p * 8 + (tid >> 5), ic4 = (tid & 31) << 2;
    const int h = ic4 >> 6, icr = ic4 & 63;
    u16* dst = xt + (size_t)h * XT_HALF_ELEMS +
               ((size_t)(((b * NP + z + 1) * NP + (yq + 1)) * NP + (xx + 1))) * 64 +
               icr;
    *(ushort4*)dst = *(const ushort4*)&t[xx * 132 + ic4];
  }
}

// ---------------- kernel 4: B-direct conv, ic-half-major phase order ------
// Block: 128 oc x 256 n (8y x 32x) at fixed (b,z). 4 waves 1x4, wave tile
// 128x64. 54 phases p: h = p/27 (ic half, OUTER), t = p%27 (tap).
// A (wmod) in LDS, dbuf by phase parity, staged 2 phases ahead.
// B direct from xt (L2-resident: 2.66 MB/XCD working set), reg-dbuf'd.
// Steady WAITV(12) drains exactly A(p); tail WAITV(8). No vmcnt(0) in loop.
__global__ __launch_bounds__(256, 2) void kconv(const u16* __restrict__ xt,
                                                const u16* __restrict__ wmod,
                                                float* __restrict__ out) {
  __shared__ __align__(16) u16 Asm[2][1024 * 8];   // 2 x 16 KiB [oc][64ic]
  const int tid = threadIdx.x;
  const int lane = tid & 63, wn = tid >> 6;        // 4 waves along n
  const int l15 = lane & 15, sg = lane >> 4;
  const int bsw = ((blockIdx.x & 7) << 6) + (blockIdx.x >> 3);  // XCD chunks
  const int yt = bsw & 3, z = (bsw >> 2) & 31, b = bsw >> 7;
  const int y0 = yt << 3;

  const char* xbp = (const char*)xt;

  // per-lane B center byte offsets within a half (incl. batch base)
  int bofs[4];
#pragma unroll
  for (int nf = 0; nf < 4; ++nf) {
    const int yy = (wn << 1) + (nf >> 1);
    const int xx = ((nf & 1) << 4) + l15;
    bofs[nf] = b * (NP * NP * NP * 128) +
               ((((z + 1) * NP + (y0 + yy + 1)) * NP + (xx + 1)) << 7) +
               (sg << 4);
  }

  f32x4 acc[8][4];
#pragma unroll
  for (int i = 0; i < 8; ++i)
#pragma unroll
    for (int j = 0; j < 4; ++j) acc[i][j] = (f32x4){0.f, 0.f, 0.f, 0.f};

  // phase -> B byte-offset addend (half base + tap displacement)
  auto phB = [&](int p) -> int {
    const int h = p >= 27 ? 1 : 0;
    const int t = p - 27 * h;
    const int dz = t / 9 - 1, dy = (t / 3) % 3 - 1, dx = t % 3 - 1;
    return h * XT_HALF_BYTES + ((dz * NP + dy) * NP + dx) * 128;
  };
  // load 8 B fragments (4 nf x 2 kk) straight from global for phase p
  auto loadB = [&](bf16x8* bv, int p) {
    const int toff = phB(p);
#pragma unroll
    for (int nf = 0; nf < 4; ++nf)
#pragma unroll
      for (int kk = 0; kk < 2; ++kk)
        bv[nf * 2 + kk] =
            *(const bf16x8*)(xbp + (size_t)(bofs[nf] + toff + (kk << 6)));
  };
  // stage A tile of phase p: [128 oc][64 ic], 4 gload_lds/thread
  auto stageA = [&](int p, int par) {
    const int h = p >= 27 ? 1 : 0;
    const int t = p - 27 * h;
    const u16* base = wmod + ((size_t)((h * 4 + b) * 27 + t) << 13);
#pragma unroll
    for (int k = 0; k < 4; ++k) {
      const int s = (k << 8) + tid;
      const int oc = s >> 3, jp = s & 7, jg = jp ^ (oc & 7);
      gload_lds16(base + (oc << 6) + (jg << 3), &Asm[par][s << 3]);
    }
  };

#define COMPUTE(PAR, BV)                                                     \
  {                                                                          \
    _Pragma("unroll") for (int kk = 0; kk < 2; ++kk) {                       \
      bf16x8 af[8];                                                          \
      _Pragma("unroll") for (int m = 0; m < 8; ++m) {                        \
        const int oc = (m << 4) + l15;                                       \
        const int jp = ((kk << 2) + sg) ^ (oc & 7);                          \
        af[m] = *(const bf16x8*)&Asm[PAR][(oc << 6) + (jp << 3)];            \
      }                                                                      \
      __builtin_amdgcn_s_setprio(1);                                         \
      _Pragma("unroll") for (int m = 0; m < 8; ++m)                          \
        _Pragma("unroll") for (int nf = 0; nf < 4; ++nf)                     \
          acc[m][nf] = __builtin_amdgcn_mfma_f32_16x16x32_bf16(              \
              af[m], (BV)[nf * 2 + kk], acc[m][nf], 0, 0, 0);                \
      __builtin_amdgcn_s_setprio(0);                                         \
    }                                                                        \
  }

  bf16x8 bvE[8], bvO[8];
  // prologue: A(0)->Asm[0] (4), A(1)->Asm[1] (4), bvE(phase 0) (8) = 16 out
  stageA(0, 0);
  stageA(1, 1);
  loadB(bvE, 0);

  for (int q = 0; q < 26; ++q) {
    const int p0 = q << 1;
    // even phase p0: Asm[0], bvE
    WAITV(12); BAR();
    loadB(bvO, p0 + 1);
    COMPUTE(0, bvE);
    BAR();
    stageA(p0 + 2, 0);
    // odd phase p0+1: Asm[1], bvO
    WAITV(12); BAR();
    loadB(bvE, p0 + 2);
    COMPUTE(1, bvO);
    BAR();
    if (p0 + 1 <= 51) stageA(p0 + 3, 1);
  }
  {  // tail pair: phases 52, 53
    WAITV(12); BAR();
    loadB(bvO, 53);
    COMPUTE(0, bvE);
    BAR();
    // no stage (A(54) doesn't exist)
    WAITV(8); BAR();
    COMPUTE(1, bvO);
  }

  // epilogue: C/D col=l15 (n), row=sg*4+r (oc within 16)
#pragma unroll
  for (int m = 0; m < 8; ++m) {
    const int ocb = (m << 4) + (sg << 2);
#pragma unroll
    for (int nf = 0; nf < 4; ++nf) {
      const int n = (wn << 6) + (nf << 4) + l15;
      const int yy = n >> 5, xx = n & 31;
      float* op = out + ((size_t)(b * 128 + ocb) << 15) + (z << 10) +
                  ((y0 + yy) << 5) + xx;
#pragma unroll
      for (int r = 0; r < 4; ++r) op[(size_t)r << 15] = acc[m][nf][r];
    }
  }
#undef COMPUTE
}

extern "C" void kernel_launch(void* const* d_in, const int* in_sizes, int n_in,
                              void* d_out, int out_size, void* d_ws, size_t ws_size,
                              hipStream_t stream) {
  const float* x = (const float*)d_in[0];
  const float* y = (const float*)d_in[1];
  const float* w = (const float*)d_in[2];
  float* out = (float*)d_out;
  u16* xt = (u16*)d_ws;
  u16* wmod = (u16*)((char*)d_ws + XT_BYTES);

  hipLaunchKernelGGL(khalo, dim3(NP * NP, 4), dim3(128), 0, stream, xt);
  hipLaunchKernelGGL(kmodw, dim3(128, 4), dim3(128), 0, stream, w, y, wmod);
  hipLaunchKernelGGL(kcastx, dim3(32, 32, 4), dim3(256), 0, stream, x, xt);
  hipLaunchKernelGGL(kconv, dim3(512), dim3(256), 0, stream, xt, wmod, out);
}